// Round 1
// baseline (15998.497 us; speedup 1.0000x reference)
//
#include <hip/hip_runtime.h>
#include <hip/hip_bf16.h>

typedef __bf16 bf16;
typedef __bf16 bf16x8 __attribute__((ext_vector_type(8)));
typedef float  f32x4  __attribute__((ext_vector_type(4)));

// Problem constants
#define TSTEPS 512
#define BATCH  64
#define HID    1024
// x rows = T*B = 32768, gate width = 3*HID = 3072

// ---------------------------------------------------------------------------
// f32 -> bf16 straight cast, 8 elems/thread, grid sized exactly
__global__ __launch_bounds__(256) void cast_f32_bf16(const float* __restrict__ in,
                                                     bf16* __restrict__ out) {
    size_t i = ((size_t)blockIdx.x * blockDim.x + threadIdx.x) * 8;
    float4 a = *(const float4*)(in + i);
    float4 b = *(const float4*)(in + i + 4);
    bf16x8 o;
    o[0] = (bf16)a.x; o[1] = (bf16)a.y; o[2] = (bf16)a.z; o[3] = (bf16)a.w;
    o[4] = (bf16)b.x; o[5] = (bf16)b.y; o[6] = (bf16)b.z; o[7] = (bf16)b.w;
    *(bf16x8*)(out + i) = o;
}

// ---------------------------------------------------------------------------
// W[R][C] f32 (row-major) -> Wt[C][R] bf16 (row-major). R,C multiples of 32.
__global__ __launch_bounds__(256) void transpose_cast(const float* __restrict__ in,
                                                      bf16* __restrict__ out,
                                                      int R, int C) {
    __shared__ float tile[32][33];
    int c0 = blockIdx.x * 32, r0 = blockIdx.y * 32;
    int tx = threadIdx.x & 31, ty = threadIdx.x >> 5;   // ty 0..7
    #pragma unroll
    for (int i = 0; i < 32; i += 8)
        tile[ty + i][tx] = in[(size_t)(r0 + ty + i) * C + c0 + tx];
    __syncthreads();
    #pragma unroll
    for (int i = 0; i < 32; i += 8)
        out[(size_t)(c0 + ty + i) * R + r0 + tx] = (bf16)tile[tx][ty + i];
}

// ---------------------------------------------------------------------------
// C[M][N] = A[M][K] @ B[K][N] (+bias), A bf16 row-major, Bt = B^T bf16 [N][K].
// Tile 64x64, K-chunk 64, 4 waves (each wave: 16 rows x 64 cols).
template<bool BF16_OUT, bool HAS_BIAS>
__global__ __launch_bounds__(256) void gemm_bf16(const bf16* __restrict__ A,
                                                 const bf16* __restrict__ Bt,
                                                 const float* __restrict__ bias,
                                                 void* __restrict__ Cout,
                                                 int M, int N, int K) {
    __shared__ bf16 sA[64][72];   // +8 pad: 2-way max bank conflict
    __shared__ bf16 sB[64][72];
    const int tid  = threadIdx.x;
    const int lane = tid & 63, w = tid >> 6;
    const int m0 = blockIdx.y * 64, n0 = blockIdx.x * 64;

    f32x4 acc[4] = {f32x4{0,0,0,0}, f32x4{0,0,0,0}, f32x4{0,0,0,0}, f32x4{0,0,0,0}};

    const int ldr = tid >> 2;          // 0..63
    const int ldk = (tid & 3) * 16;    // 0,16,32,48
    const bf16* Ap = A  + (size_t)(m0 + ldr) * K + ldk;
    const bf16* Bp = Bt + (size_t)(n0 + ldr) * K + ldk;

    const int ml = lane & 15;
    const int kb = (lane >> 4) * 8;

    for (int kc = 0; kc < K; kc += 64) {
        *(uint4*)&sA[ldr][ldk]     = *(const uint4*)(Ap);
        *(uint4*)&sA[ldr][ldk + 8] = *(const uint4*)(Ap + 8);
        *(uint4*)&sB[ldr][ldk]     = *(const uint4*)(Bp);
        *(uint4*)&sB[ldr][ldk + 8] = *(const uint4*)(Bp + 8);
        Ap += 64; Bp += 64;
        __syncthreads();
        #pragma unroll
        for (int ks = 0; ks < 2; ++ks) {
            bf16x8 af = *(const bf16x8*)&sA[w * 16 + ml][ks * 32 + kb];
            #pragma unroll
            for (int nf = 0; nf < 4; ++nf) {
                bf16x8 bfrag = *(const bf16x8*)&sB[nf * 16 + ml][ks * 32 + kb];
                acc[nf] = __builtin_amdgcn_mfma_f32_16x16x32_bf16(af, bfrag, acc[nf], 0, 0, 0);
            }
        }
        __syncthreads();
    }
    // epilogue: D lane map: col = lane&15, row = (lane>>4)*4 + reg
    const int rbase = (lane >> 4) * 4;
    #pragma unroll
    for (int nf = 0; nf < 4; ++nf) {
        int col = n0 + nf * 16 + ml;
        float bv = HAS_BIAS ? bias[col] : 0.f;
        #pragma unroll
        for (int r = 0; r < 4; ++r) {
            int row = m0 + w * 16 + rbase + r;
            float v = acc[nf][r] + bv;
            if constexpr (BF16_OUT)
                ((bf16*)Cout)[(size_t)row * N + col] = (bf16)v;
            else
                ((float*)Cout)[(size_t)row * N + col] = v;
        }
    }
}

// ---------------------------------------------------------------------------
// One GRU time step.  grid = 64 blocks (16 H-cols each), 256 threads (4 waves,
// wave w owns batch rows 16w..16w+15).  gh = h @ Whh for the block's 48 cols
// (3 gates x 16), then gate math + state update.
// h kept in f32 (carried state, exact) + bf16 (MFMA operand).
__global__ __launch_bounds__(256) void gru_step(const bf16*  __restrict__ h_bf,
                                                const float* __restrict__ h_f32,
                                                const bf16*  __restrict__ WhhT,  // [3072][1024]
                                                const bf16*  __restrict__ gx,    // [T*64][3072]
                                                const float* __restrict__ pad,   // [T][64]
                                                int t,
                                                bf16*  __restrict__ h_bf_out,
                                                float* __restrict__ h_f32_out,
                                                bf16*  __restrict__ hs) {        // [T*64][1024]
    __shared__ bf16 sH[64][264];   // 64 batch rows x 256-k chunk (+8 pad)
    __shared__ bf16 sW[48][264];   // 48 gate-cols x 256-k chunk

    const int tid  = threadIdx.x;
    const int lane = tid & 63, w = tid >> 6;
    const int j0   = blockIdx.x * 16;
    const int ml   = lane & 15;
    const int kb   = (lane >> 4) * 8;

    f32x4 acc[3] = {f32x4{0,0,0,0}, f32x4{0,0,0,0}, f32x4{0,0,0,0}};

    const int sr = tid >> 2;            // 0..63
    const int sc = (tid & 3) * 64;      // 0,64,128,192

    for (int kc = 0; kc < 1024; kc += 256) {
        // stage h chunk: 64 x 256
        {
            const bf16* src = h_bf + (size_t)sr * 1024 + kc + sc;
            #pragma unroll
            for (int i = 0; i < 8; ++i)
                *(uint4*)&sH[sr][sc + i * 8] = *(const uint4*)(src + i * 8);
        }
        // stage Whh chunk: 48 x 256 (rows: gate*16+n -> WhhT row gate*1024+j0+n)
        if (tid < 192) {
            int r = sr;                       // 0..47
            int grow = (r >> 4) * 1024 + j0 + (r & 15);
            const bf16* src = WhhT + (size_t)grow * 1024 + kc + sc;
            #pragma unroll
            for (int i = 0; i < 8; ++i)
                *(uint4*)&sW[r][sc + i * 8] = *(const uint4*)(src + i * 8);
        }
        __syncthreads();
        #pragma unroll
        for (int ks = 0; ks < 8; ++ks) {
            bf16x8 af = *(const bf16x8*)&sH[w * 16 + ml][ks * 32 + kb];
            #pragma unroll
            for (int g = 0; g < 3; ++g) {
                bf16x8 bfrag = *(const bf16x8*)&sW[g * 16 + ml][ks * 32 + kb];
                acc[g] = __builtin_amdgcn_mfma_f32_16x16x32_bf16(af, bfrag, acc[g], 0, 0, 0);
            }
        }
        __syncthreads();
    }

    // epilogue: lane holds rows (lane>>4)*4+r, col j0+(lane&15), for its wave's 16-row band
    const int j = j0 + ml;
    const int rbase = (lane >> 4) * 4;
    const bf16* gxt = gx + (size_t)t * 64 * 3072;
    #pragma unroll
    for (int r = 0; r < 4; ++r) {
        int b = w * 16 + rbase + r;
        float ghr = acc[0][r], ghz = acc[1][r], ghn = acc[2][r];
        float gxr = (float)gxt[(size_t)b * 3072 + j];
        float gxz = (float)gxt[(size_t)b * 3072 + 1024 + j];
        float gxn = (float)gxt[(size_t)b * 3072 + 2048 + j];
        float rr = 1.f / (1.f + __expf(-(gxr + ghr)));
        float zz = 1.f / (1.f + __expf(-(gxz + ghz)));
        float nn = tanhf(gxn + rr * ghn);
        float hold = h_f32[(size_t)b * 1024 + j];
        float hn = (1.f - zz) * nn + zz * hold;
        float pt = pad[t * 64 + b];
        hn = pt * hold + (1.f - pt) * hn;
        h_f32_out[(size_t)b * 1024 + j] = hn;
        bf16 hb = (bf16)hn;
        h_bf_out[(size_t)b * 1024 + j] = hb;
        hs[((size_t)t * 64 + b) * 1024 + j] = hb;
    }
}

// ---------------------------------------------------------------------------
extern "C" void kernel_launch(void* const* d_in, const int* in_sizes, int n_in,
                              void* d_out, int out_size, void* d_ws, size_t ws_size,
                              hipStream_t stream) {
    const float* x      = (const float*)d_in[0];
    const float* pad    = (const float*)d_in[1];
    const float* Wih[2] = {(const float*)d_in[2], (const float*)d_in[6]};
    const float* Whh[2] = {(const float*)d_in[3], (const float*)d_in[7]};
    const float* bias[2]= {(const float*)d_in[4], (const float*)d_in[8]};
    const float* Who[2] = {(const float*)d_in[5], (const float*)d_in[9]};
    float* out_f = (float*)d_out;

    char* p = (char*)d_ws;
    bf16* xb   = (bf16*)p;  p += (size_t)32768 * 1024 * 2;   //  64 MB
    bf16* gxb  = (bf16*)p;  p += (size_t)32768 * 3072 * 2;   // 192 MB
    bf16* hsb  = (bf16*)p;  p += (size_t)32768 * 1024 * 2;   //  64 MB
    bf16* WihT = (bf16*)p;  p += (size_t)3072 * 1024 * 2;
    bf16* WhhT = (bf16*)p;  p += (size_t)3072 * 1024 * 2;
    bf16* WhoT = (bf16*)p;  p += (size_t)1024 * 1024 * 2;
    bf16* hb0  = (bf16*)p;  p += (size_t)64 * 1024 * 2;
    bf16* hb1  = (bf16*)p;  p += (size_t)64 * 1024 * 2;
    float* hf0 = (float*)p; p += (size_t)64 * 1024 * 4;
    float* hf1 = (float*)p; p += (size_t)64 * 1024 * 4;

    // x -> bf16  (33554432 elems / 8 per thread / 256 per block)
    cast_f32_bf16<<<16384, 256, 0, stream>>>(x, xb);

    for (int L = 0; L < 2; ++L) {
        transpose_cast<<<dim3(96, 32), 256, 0, stream>>>(Wih[L], WihT, 1024, 3072);
        transpose_cast<<<dim3(96, 32), 256, 0, stream>>>(Whh[L], WhhT, 1024, 3072);
        transpose_cast<<<dim3(32, 32), 256, 0, stream>>>(Who[L], WhoT, 1024, 1024);

        // gx = x @ Wih + b : M=32768, N=3072, K=1024, bf16 out
        gemm_bf16<true, true><<<dim3(48, 512), 256, 0, stream>>>(
            xb, WihT, bias[L], gxb, 32768, 3072, 1024);

        hipMemsetAsync(hb0, 0, (size_t)64 * 1024 * 2, stream);
        hipMemsetAsync(hf0, 0, (size_t)64 * 1024 * 4, stream);

        for (int t = 0; t < 512; ++t) {
            bf16*  hbi = (t & 1) ? hb1 : hb0;
            bf16*  hbo = (t & 1) ? hb0 : hb1;
            float* hfi = (t & 1) ? hf1 : hf0;
            float* hfo = (t & 1) ? hf0 : hf1;
            gru_step<<<64, 256, 0, stream>>>(hbi, hfi, WhhT, gxb, pad, t, hbo, hfo, hsb);
        }

        // out = hs @ Who : M=32768, N=1024, K=1024, f32 out into d_out
        gemm_bf16<false, false><<<dim3(16, 512), 256, 0, stream>>>(
            hsb, WhoT, nullptr, out_f, 32768, 1024, 1024);

        if (L == 0) {
            // layer-2 input = layer-1 output, cast to bf16
            cast_f32_bf16<<<16384, 256, 0, stream>>>(out_f, xb);
        }
    }
}